// Round 2
// baseline (513.091 us; speedup 1.0000x reference)
//
#include <hip/hip_runtime.h>
#include <hip/hip_bf16.h>

// Problem constants (from reference)
#define NUSERS   10000
#define NITEMS   100000
#define DIM      64
#define BATCH    4096

// GEMM tiling
#define KPAD     10240          // 320 * 32, zero-padded K (constant trip counts)
#define SPC      16             // K-steps (of 32) per chunk
#define NCHUNK   20             // 320 / 16
#define MT       64             // batch rows per block (4 waves x 16 rows)

typedef __bf16 bf16_t;
typedef __bf16 bf16x8 __attribute__((ext_vector_type(8)));
typedef float  f32x4  __attribute__((ext_vector_type(4)));

// ---------------------------------------------------------------------------
// Kernel 1: transpose + convert user_emb[k][d] (f32) -> ueT[d][k] (bf16),
// k zero-padded to KPAD so the GEMM K-loop needs no bounds checks on B.
// ueT is 64*10240*2 B = 1.31 MB -> L2-resident during the GEMM.
// ---------------------------------------------------------------------------
__global__ void prep_ueT_kernel(const float* __restrict__ user_emb,
                                bf16_t* __restrict__ ueT) {
    int d = blockIdx.y;
    int k = blockIdx.x * 256 + threadIdx.x;
    float v = (k < NUSERS) ? user_emb[(size_t)k * DIM + d] : 0.0f;
    ueT[(size_t)d * KPAD + k] = (bf16_t)v;
}

// ---------------------------------------------------------------------------
// Kernel 2: out[b] = dot(user_emb[users[b]], item_emb[items[b]])
// Plain store — initializes d_out (poisoned by harness) before social atomics.
// One wave per batch element.
// ---------------------------------------------------------------------------
__global__ void pos_kernel(const float* __restrict__ user_emb,
                           const float* __restrict__ item_emb,
                           const int* __restrict__ users,
                           const int* __restrict__ items,
                           float* __restrict__ out) {
    int w    = threadIdx.x >> 6;
    int lane = threadIdx.x & 63;
    int b    = blockIdx.x * 4 + w;
    if (b >= BATCH) return;
    int uid = users[b];
    int iid = items[b];
    float v = user_emb[(size_t)uid * DIM + lane] * item_emb[(size_t)iid * DIM + lane];
    v += __shfl_xor(v, 32, 64);
    v += __shfl_xor(v, 16, 64);
    v += __shfl_xor(v, 8, 64);
    v += __shfl_xor(v, 4, 64);
    v += __shfl_xor(v, 2, 64);
    v += __shfl_xor(v, 1, 64);
    if (lane == 0) out[b] = v;
}

// ---------------------------------------------------------------------------
// Kernel 3: social term — barrier-free, LDS-free.
//   V[m, d] = sum_k sw[users[m], k] * user_emb[k, d]   (bf16 MFMA GEMM)
//   out[m] += sum_d V[m, d] * item_emb[items[m], d]    (epilogue, atomicAdd)
//
// MFMA fragments are loaded DIRECTLY from global memory:
//   A-layout (16x16x32): lane = c + 16q holds A[m=c][k=8q+j], j=0..7
//     -> 32 B contiguous from sw[users[m0+16w+c]][k0+8q ...], cvt f32->bf16.
//   B-layout:            lane = c + 16q holds B[k=8q+j][n=c]
//     -> 16 B contiguous from ueT[n][k0+8q ...] (L2-resident).
// No __syncthreads in the K-loop: the compiler pipelines the 6 loads per
// step across iterations; waves are fully independent.
// Grid: x = K-chunk (20), y = M-tile (64). Each wave: 16 rows x 64 cols.
// ---------------------------------------------------------------------------
__global__ __launch_bounds__(256) void social_kernel(
        const float* __restrict__ sw,
        const bf16_t* __restrict__ ueT,
        const float* __restrict__ item_emb,
        const int* __restrict__ users,
        const int* __restrict__ items,
        float* __restrict__ out) {
    const int tid  = threadIdx.x;
    const int w    = tid >> 6;       // wave id: rows [16w, 16w+16)
    const int lane = tid & 63;
    const int q    = lane >> 4;      // quad group 0..3 -> k-offset 8q
    const int c    = lane & 15;      // A row within tile / B col

    const int m0   = blockIdx.y * MT;
    const int arow = m0 + 16 * w + c;
    const int uid  = users[arow];
    const float*  ap  = sw + (size_t)uid * NUSERS;       // lane's sw row
    const bf16_t* bp0 = ueT + (size_t)(c     ) * KPAD;
    const bf16_t* bp1 = ueT + (size_t)(c + 16) * KPAD;
    const bf16_t* bp2 = ueT + (size_t)(c + 32) * KPAD;
    const bf16_t* bp3 = ueT + (size_t)(c + 48) * KPAD;

    f32x4 acc0 = {0.f, 0.f, 0.f, 0.f};
    f32x4 acc1 = {0.f, 0.f, 0.f, 0.f};
    f32x4 acc2 = {0.f, 0.f, 0.f, 0.f};
    f32x4 acc3 = {0.f, 0.f, 0.f, 0.f};

    int k = blockIdx.x * (SPC * 32) + 8 * q;

    #pragma unroll 2
    for (int s = 0; s < SPC; ++s, k += 32) {
        // A: 8 floats from the gathered sw row (guard: K zero-pad region).
        float4 a0 = {0.f, 0.f, 0.f, 0.f};
        float4 a1 = {0.f, 0.f, 0.f, 0.f};
        if (k < NUSERS) {            // k % 8 == 0, NUSERS % 8 == 0
            const float4* p = (const float4*)(ap + k);
            a0 = p[0];
            a1 = p[1];
        }
        // B: 4 fragments from ueT (L2-resident, zero-padded to KPAD).
        const bf16x8 b0 = *(const bf16x8*)(bp0 + k);
        const bf16x8 b1 = *(const bf16x8*)(bp1 + k);
        const bf16x8 b2 = *(const bf16x8*)(bp2 + k);
        const bf16x8 b3 = *(const bf16x8*)(bp3 + k);

        bf16x8 av;
        av[0] = (bf16_t)a0.x; av[1] = (bf16_t)a0.y;
        av[2] = (bf16_t)a0.z; av[3] = (bf16_t)a0.w;
        av[4] = (bf16_t)a1.x; av[5] = (bf16_t)a1.y;
        av[6] = (bf16_t)a1.z; av[7] = (bf16_t)a1.w;

        acc0 = __builtin_amdgcn_mfma_f32_16x16x32_bf16(av, b0, acc0, 0, 0, 0);
        acc1 = __builtin_amdgcn_mfma_f32_16x16x32_bf16(av, b1, acc1, 0, 0, 0);
        acc2 = __builtin_amdgcn_mfma_f32_16x16x32_bf16(av, b2, acc2, 0, 0, 0);
        acc3 = __builtin_amdgcn_mfma_f32_16x16x32_bf16(av, b3, acc3, 0, 0, 0);
    }

    // Epilogue: C/D layout (verified m89): col = lane&15, row = (lane>>4)*4 + r.
    // Local row = 16w + 4q + r; acc_t element column = 16t + c.
    for (int r = 0; r < 4; ++r) {
        const int grow = m0 + 16 * w + 4 * q + r;
        const int iid  = items[grow];          // uniform across the 16-lane group
        const float* ie = item_emb + (size_t)iid * DIM;
        float v = acc0[r] * ie[c]
                + acc1[r] * ie[c + 16]
                + acc2[r] * ie[c + 32]
                + acc3[r] * ie[c + 48];
        // reduce across the 16 lanes (c = 0..15) holding this row
        v += __shfl_xor(v, 1, 64);
        v += __shfl_xor(v, 2, 64);
        v += __shfl_xor(v, 4, 64);
        v += __shfl_xor(v, 8, 64);
        if (c == 0) atomicAdd(out + grow, v);
    }
}

// ---------------------------------------------------------------------------
extern "C" void kernel_launch(void* const* d_in, const int* in_sizes, int n_in,
                              void* d_out, int out_size, void* d_ws, size_t ws_size,
                              hipStream_t stream) {
    const float* user_emb = (const float*)d_in[0];
    const float* item_emb = (const float*)d_in[1];
    const float* sw       = (const float*)d_in[2];
    const int*   users    = (const int*)d_in[3];
    const int*   items    = (const int*)d_in[4];
    float* out = (float*)d_out;

    bf16_t* ueT = (bf16_t*)d_ws;   // DIM * KPAD bf16 = 1.31 MB

    // 1) transpose+convert user_emb (runs every call; ws is re-poisoned)
    prep_ueT_kernel<<<dim3(KPAD / 256, DIM), 256, 0, stream>>>(user_emb, ueT);

    // 2) positive dot, initializes out
    pos_kernel<<<BATCH / 4, 256, 0, stream>>>(user_emb, item_emb, users, items, out);

    // 3) social GEMM + fused epilogue dot, atomic accumulate into out
    social_kernel<<<dim3(NCHUNK, BATCH / MT), 256, 0, stream>>>(
        sw, ueT, item_emb, users, items, out);
}

// Round 3
// 499.376 us; speedup vs baseline: 1.0275x; 1.0275x over previous
//
#include <hip/hip_runtime.h>
#include <hip/hip_bf16.h>

// Problem constants (from reference)
#define NUSERS   10000
#define NITEMS   100000
#define DIM      64
#define BATCH    4096

// GEMM tiling
#define KPAD     10240          // 320 * 32, zero-padded K
#define SPC      20             // K-steps (of 32) per chunk
#define NCHUNK   16             // 16 * 20 * 32 = 10240 = KPAD
#define MT       64             // batch rows per block (4 waves x 16 rows)

// prep/pos combined-kernel block partition
#define PREP_BLOCKS (KPAD / 64)     // 160: one 64-row k-tile each
#define POS_BLOCKS  (BATCH / 4)     // 1024: 4 waves -> 4 batch elems each

typedef __bf16 bf16_t;
typedef __bf16 bf16x8 __attribute__((ext_vector_type(8)));
typedef float  f32x4  __attribute__((ext_vector_type(4)));

// ---------------------------------------------------------------------------
// Kernel 1 (fused): blocks [0,160): transpose+convert user_emb[k][d] (f32)
// -> ueT[d][k] (bf16, k zero-padded to KPAD) via an LDS tile so both global
// sides are vectorized. Blocks [160, 160+1024): pos dot
// out[b] = dot(user_emb[users[b]], item_emb[items[b]]) — plain store, which
// initializes the poisoned d_out before social's atomics.
// ---------------------------------------------------------------------------
__global__ __launch_bounds__(256) void prep_pos_kernel(
        const float* __restrict__ user_emb,
        const float* __restrict__ item_emb,
        const int* __restrict__ users,
        const int* __restrict__ items,
        bf16_t* __restrict__ ueT,
        float* __restrict__ out) {
    __shared__ bf16_t tile[64 * 72];   // [k_local][d], pad 64->72 (9.2 KB)

    const int tid = threadIdx.x;

    if (blockIdx.x < PREP_BLOCKS) {
        // ---- prep: k-tile [k0, k0+64) x d[0,64) ----
        const int k0  = blockIdx.x * 64;
        const int r   = tid >> 2;        // k_local 0..63
        const int seg = tid & 3;         // d segment: 16 floats
        const int krow = k0 + r;

        float4 f0 = {0.f,0.f,0.f,0.f}, f1 = f0, f2 = f0, f3 = f0;
        if (krow < NUSERS) {
            const float4* p = (const float4*)(user_emb + (size_t)krow * DIM + 16 * seg);
            f0 = p[0]; f1 = p[1]; f2 = p[2]; f3 = p[3];
        }
        bf16x8 v0, v1;
        v0[0]=(bf16_t)f0.x; v0[1]=(bf16_t)f0.y; v0[2]=(bf16_t)f0.z; v0[3]=(bf16_t)f0.w;
        v0[4]=(bf16_t)f1.x; v0[5]=(bf16_t)f1.y; v0[6]=(bf16_t)f1.z; v0[7]=(bf16_t)f1.w;
        v1[0]=(bf16_t)f2.x; v1[1]=(bf16_t)f2.y; v1[2]=(bf16_t)f2.z; v1[3]=(bf16_t)f2.w;
        v1[4]=(bf16_t)f3.x; v1[5]=(bf16_t)f3.y; v1[6]=(bf16_t)f3.z; v1[7]=(bf16_t)f3.w;
        *(bf16x8*)(tile + r * 72 + 16 * seg)     = v0;
        *(bf16x8*)(tile + r * 72 + 16 * seg + 8) = v1;
        __syncthreads();

        // write transposed: thread -> d = tid>>2, k segment of 16
        const int d    = tid >> 2;
        const int kseg = tid & 3;
        bf16x8 o0, o1;
        #pragma unroll
        for (int i = 0; i < 8; ++i) {
            o0[i] = tile[(16 * kseg + i    ) * 72 + d];
            o1[i] = tile[(16 * kseg + i + 8) * 72 + d];
        }
        bf16_t* dst = ueT + (size_t)d * KPAD + k0 + 16 * kseg;
        *(bf16x8*)(dst)     = o0;
        *(bf16x8*)(dst + 8) = o1;
    } else {
        // ---- pos: one wave per batch element ----
        const int w    = tid >> 6;
        const int lane = tid & 63;
        const int b    = (blockIdx.x - PREP_BLOCKS) * 4 + w;
        const int uid = users[b];
        const int iid = items[b];
        float v = user_emb[(size_t)uid * DIM + lane] * item_emb[(size_t)iid * DIM + lane];
        v += __shfl_xor(v, 32, 64);
        v += __shfl_xor(v, 16, 64);
        v += __shfl_xor(v, 8, 64);
        v += __shfl_xor(v, 4, 64);
        v += __shfl_xor(v, 2, 64);
        v += __shfl_xor(v, 1, 64);
        if (lane == 0) out[b] = v;
    }
}

// ---------------------------------------------------------------------------
// Kernel 2: social term — barrier-free, LDS-free.
//   V[m, d] = sum_k sw[users[m], k] * user_emb[k, d]   (bf16 MFMA GEMM)
//   out[m] += sum_d V[m, d] * item_emb[items[m], d]    (epilogue, atomicAdd)
// MFMA fragments loaded directly from global:
//   A (16x16x32): lane c+16q holds A[m=c][k=8q+j] -> 32 B contiguous from the
//   gathered sw row (f32 -> bf16 in-register). B: lane holds B[k=8q+j][n=c]
//   -> 16 B contiguous from ueT row n (L2-resident, zero-padded).
// Grid: x = K-chunk (16), y = M-tile (64) -> 1024 blocks = 4 / CU.
// ---------------------------------------------------------------------------
__global__ __launch_bounds__(256) void social_kernel(
        const float* __restrict__ sw,
        const bf16_t* __restrict__ ueT,
        const float* __restrict__ item_emb,
        const int* __restrict__ users,
        const int* __restrict__ items,
        float* __restrict__ out) {
    const int tid  = threadIdx.x;
    const int w    = tid >> 6;       // wave id: rows [16w, 16w+16)
    const int lane = tid & 63;
    const int q    = lane >> 4;      // quad group 0..3 -> k-offset 8q
    const int c    = lane & 15;      // A row within tile / B col

    const int m0   = blockIdx.y * MT;
    const int arow = m0 + 16 * w + c;
    const int uid  = users[arow];
    const float*  ap  = sw + (size_t)uid * NUSERS;       // lane's sw row
    const bf16_t* bp0 = ueT + (size_t)(c     ) * KPAD;
    const bf16_t* bp1 = ueT + (size_t)(c + 16) * KPAD;
    const bf16_t* bp2 = ueT + (size_t)(c + 32) * KPAD;
    const bf16_t* bp3 = ueT + (size_t)(c + 48) * KPAD;

    f32x4 acc0 = {0.f, 0.f, 0.f, 0.f};
    f32x4 acc1 = {0.f, 0.f, 0.f, 0.f};
    f32x4 acc2 = {0.f, 0.f, 0.f, 0.f};
    f32x4 acc3 = {0.f, 0.f, 0.f, 0.f};

    int k = blockIdx.x * (SPC * 32) + 8 * q;

    #pragma unroll 2
    for (int s = 0; s < SPC; ++s, k += 32) {
        // A: 8 floats from the gathered sw row (guard: K zero-pad region).
        float4 a0 = {0.f, 0.f, 0.f, 0.f};
        float4 a1 = {0.f, 0.f, 0.f, 0.f};
        if (k < NUSERS) {            // k % 8 == 0, NUSERS % 8 == 0
            const float4* p = (const float4*)(ap + k);
            a0 = p[0];
            a1 = p[1];
        }
        // B: 4 fragments from ueT (L2-resident, zero-padded to KPAD).
        const bf16x8 b0 = *(const bf16x8*)(bp0 + k);
        const bf16x8 b1 = *(const bf16x8*)(bp1 + k);
        const bf16x8 b2 = *(const bf16x8*)(bp2 + k);
        const bf16x8 b3 = *(const bf16x8*)(bp3 + k);

        bf16x8 av;
        av[0] = (bf16_t)a0.x; av[1] = (bf16_t)a0.y;
        av[2] = (bf16_t)a0.z; av[3] = (bf16_t)a0.w;
        av[4] = (bf16_t)a1.x; av[5] = (bf16_t)a1.y;
        av[6] = (bf16_t)a1.z; av[7] = (bf16_t)a1.w;

        acc0 = __builtin_amdgcn_mfma_f32_16x16x32_bf16(av, b0, acc0, 0, 0, 0);
        acc1 = __builtin_amdgcn_mfma_f32_16x16x32_bf16(av, b1, acc1, 0, 0, 0);
        acc2 = __builtin_amdgcn_mfma_f32_16x16x32_bf16(av, b2, acc2, 0, 0, 0);
        acc3 = __builtin_amdgcn_mfma_f32_16x16x32_bf16(av, b3, acc3, 0, 0, 0);
    }

    // Epilogue: C/D layout (verified m89): col = lane&15, row = (lane>>4)*4 + r.
    for (int r = 0; r < 4; ++r) {
        const int grow = m0 + 16 * w + 4 * q + r;
        const int iid  = items[grow];          // uniform across the 16-lane group
        const float* ie = item_emb + (size_t)iid * DIM;
        float v = acc0[r] * ie[c]
                + acc1[r] * ie[c + 16]
                + acc2[r] * ie[c + 32]
                + acc3[r] * ie[c + 48];
        v += __shfl_xor(v, 1, 64);
        v += __shfl_xor(v, 2, 64);
        v += __shfl_xor(v, 4, 64);
        v += __shfl_xor(v, 8, 64);
        if (c == 0) atomicAdd(out + grow, v);
    }
}

// ---------------------------------------------------------------------------
extern "C" void kernel_launch(void* const* d_in, const int* in_sizes, int n_in,
                              void* d_out, int out_size, void* d_ws, size_t ws_size,
                              hipStream_t stream) {
    const float* user_emb = (const float*)d_in[0];
    const float* item_emb = (const float*)d_in[1];
    const float* sw       = (const float*)d_in[2];
    const int*   users    = (const int*)d_in[3];
    const int*   items    = (const int*)d_in[4];
    float* out = (float*)d_out;

    bf16_t* ueT = (bf16_t*)d_ws;   // DIM * KPAD bf16 = 1.31 MB

    // 1) fused: ueT transpose/convert + pos dot (also initializes d_out)
    prep_pos_kernel<<<PREP_BLOCKS + POS_BLOCKS, 256, 0, stream>>>(
        user_emb, item_emb, users, items, ueT, out);

    // 2) social GEMM + fused epilogue dot, atomic accumulate into out
    social_kernel<<<dim3(NCHUNK, BATCH / MT), 256, 0, stream>>>(
        sw, ueT, item_emb, users, items, out);
}